// Round 7
// baseline (1139.248 us; speedup 1.0000x reference)
//
#include <hip/hip_runtime.h>
#include <hip/hip_bf16.h>
#include <math.h>
#include <stdint.h>

// Problem constants (fixed by setup_inputs)
constexpr int B_ = 4, N_ = 4096, F_ = 256;
constexpr int DS = 80;
constexpr int MAXLIST = 1 << 19;
constexpr int MAXC = 16384;  // hard bound: K_b <= N, B=4

typedef _Float16 f16;
typedef f16 f16x4 __attribute__((ext_vector_type(4)));
typedef f16 f16x8 __attribute__((ext_vector_type(8)));
typedef float f32x4 __attribute__((ext_vector_type(4)));

// async global->LDS, 16B per lane; LDS dest is wave-uniform base + lane*16
#define GLD16(gp, lp)                                                                      \
  __builtin_amdgcn_global_load_lds(                                                        \
      reinterpret_cast<const __attribute__((address_space(1))) unsigned int*>(             \
          reinterpret_cast<uintptr_t>(gp)),                                                \
      reinterpret_cast<__attribute__((address_space(3))) unsigned int*>(                   \
          reinterpret_cast<uintptr_t>(lp)),                                                \
      16, 0, 0)

// ---------------------------------------------------------------------------
// Fused: fp32->f16 convert (hi only) + row sumsq + p/q init. Block = 4 rows.
// No lo array: distmf is hi-only; borderline pairs (|d2-thr2|<0.15) go through
// the exact fp32 fixup path, so threshold decisions stay bit-exact.
__global__ __launch_bounds__(256) void pre_kernel(const float* __restrict__ x,
                                                  float* __restrict__ sq,
                                                  f16* __restrict__ xhi,
                                                  int* __restrict__ p, int* __restrict__ q,
                                                  int* __restrict__ mcnt) {
  const int blk = blockIdx.x, tid = threadIdx.x;
  const int i = blk * 256 + tid;  // float4 index
  float4 v = ((const float4*)x)[i];
  f16x4 h;
  h[0] = (f16)v.x; h[1] = (f16)v.y; h[2] = (f16)v.z; h[3] = (f16)v.w;
  ((f16x4*)xhi)[i] = h;
  float s = v.x * v.x + v.y * v.y + v.z * v.z + v.w * v.w;
  for (int off = 32; off > 0; off >>= 1) s += __shfl_down(s, off);
  const int lane = tid & 63, w = tid >> 6;
  if (lane == 0) sq[blk * 4 + w] = s;  // one wave == one 256-float row
  if (blk < 64) {
    int idx = blk * 256 + tid;
    p[idx] = -1; q[idx] = -1;
    if (idx == 0) mcnt[0] = 0;
  }
}

// ---------------------------------------------------------------------------
// MFMA hi-only pairwise-distance kernel. 128x128 lower-triangle tiles,
// XCD-pinned batches (b = bid&3). EXACT R3 skeleton (measured 140us with 3x
// the MFMAs): full double-buffer, prefetch-before-MFMA, ONE barrier per step.
// 16 MFMAs/step, single acc[16] (64 AGPR). launch_bounds(256,2) for register
// slack — actual ~130 unified regs should still yield 3 blocks/CU.
__global__ __launch_bounds__(256, 2) void distmf_kernel(
    const f16* __restrict__ xhi,
    const float* __restrict__ sq, int* __restrict__ p, int* __restrict__ q,
    int* __restrict__ mlist, int* __restrict__ mcnt) {
  const int bid = blockIdx.x;
  const int b = bid & 3;          // XCD k (bid%8) -> fixed batch (k&3): 2MB/XCD L2-resident
  const int t = bid >> 2;
  int ti = (int)((sqrtf(8.f * (float)t + 1.f) - 1.f) * 0.5f);
  while ((ti + 1) * (ti + 2) / 2 <= t) ++ti;
  while (ti * (ti + 1) / 2 > t) --ti;
  const int tj = t - ti * (ti + 1) / 2;
  const int i0 = ti * 128, j0 = tj * 128;

  __shared__ __align__(16) f16 Ah[2][4096], Bh[2][4096];
  __shared__ float sqi_s[128], sqj_s[128];
  __shared__ int smq[128], smp[128], scq[128];

  const int tid = threadIdx.x;
  const int w = tid >> 6, lane = tid & 63;
  const size_t bOff = (size_t)b * N_ * F_;
  const f16* Ahg = xhi + bOff + (size_t)i0 * F_;
  const f16* Bhg = xhi + bOff + (size_t)j0 * F_;

  // staging: chunk g = part*256 + w*64 + lane; kq = g>>7, row = g&127
  const int g1 = w * 64 + lane, g2 = 256 + g1;
  const size_t o1 = (size_t)(g1 & 127) * F_ + (size_t)(g1 >> 7) * 8;
  const size_t o2 = (size_t)(g2 & 127) * F_ + (size_t)(g2 >> 7) * 8;
  const int d1 = w * 64 * 8;
  const int d2e = d1 + 2048;

  // prologue: stage step 0 into buf 0
  GLD16(Ahg + o1, &Ah[0][d1]);
  GLD16(Ahg + o2, &Ah[0][d2e]);
  GLD16(Bhg + o1, &Bh[0][d1]);
  GLD16(Bhg + o2, &Bh[0][d2e]);

  if (tid < 128) {
    sqi_s[tid] = sq[(size_t)b * N_ + i0 + tid];
    sqj_s[tid] = sq[(size_t)b * N_ + j0 + tid];
    smq[tid] = -1; smp[tid] = -1; scq[tid] = -1;
  }

  f32x4 acc[16];
  const f32x4 zero4 = {0.f, 0.f, 0.f, 0.f};
#pragma unroll
  for (int i2 = 0; i2 < 16; ++i2) acc[i2] = zero4;

  const int wm = w >> 1, wn = w & 1;
  const int mlane = lane & 15, qd = lane >> 4;
  __syncthreads();

#pragma unroll
  for (int step = 0; step < 8; ++step) {
    const int cur = step & 1, nxt = cur ^ 1;
    // fragment reads from buf cur
    f16x8 ah[4], bh[4];
#pragma unroll
    for (int mi = 0; mi < 4; ++mi) {
      int ch = (qd * 128 + wm * 64 + mi * 16 + mlane) * 8;
      ah[mi] = *(const f16x8*)&Ah[cur][ch];
    }
#pragma unroll
    for (int nj = 0; nj < 4; ++nj) {
      int ch = (qd * 128 + wn * 64 + nj * 16 + mlane) * 8;
      bh[nj] = *(const f16x8*)&Bh[cur][ch];
    }
    // prefetch next K-slab into the other buffer BEFORE the MFMA block
    if (step < 7) {
      const size_t k0 = (size_t)(step + 1) * 32;
      GLD16(Ahg + o1 + k0, &Ah[nxt][d1]);
      GLD16(Ahg + o2 + k0, &Ah[nxt][d2e]);
      GLD16(Bhg + o1 + k0, &Bh[nxt][d1]);
      GLD16(Bhg + o2 + k0, &Bh[nxt][d2e]);
    }
#pragma unroll
    for (int mi = 0; mi < 4; ++mi)
#pragma unroll
      for (int nj = 0; nj < 4; ++nj)
        acc[mi * 4 + nj] = __builtin_amdgcn_mfma_f32_16x16x32_f16(ah[mi], bh[nj], acc[mi * 4 + nj], 0, 0, 0);
    __syncthreads();
  }

  // Epilogue: fp32 band test. hi-only dot error std ~1.3e-2 in d2; EPS=0.15
  // (~11.5 sigma). Borderline pairs -> exact fixup.
  const float THR2F = (float)((double)22.63f * (double)22.63f);
  const float EPS = 0.15f;
  const float thr_lo = THR2F - EPS, thr_hi = THR2F + EPS;
  int cqv[4] = {-1, -1, -1, -1};
#pragma unroll
  for (int mi = 0; mi < 4; ++mi) {
#pragma unroll
    for (int e = 0; e < 4; ++e) {
      const int li = wm * 64 + mi * 16 + qd * 4 + e;
      const int gi = i0 + li;
      const float sqi = sqi_s[li];
      int rqv = -1, rpv = -1;
#pragma unroll
      for (int nj = 0; nj < 4; ++nj) {
        const int idx = mi * 4 + nj;
        const int lj = wn * 64 + nj * 16 + mlane;
        const int gj = j0 + lj;
        float d2 = sqi + sqj_s[lj] - 2.0f * acc[idx][e];
        if (gj <= gi) {
          if (d2 < thr_lo) {
            rqv = max(rqv, gj);
            if (gj < gi) rpv = max(rpv, gj);
            cqv[nj] = max(cqv[nj], gi);
          } else if (d2 < thr_hi) {
            int pos = atomicAdd(mcnt, 1);
            if (pos < MAXLIST) mlist[pos] = (b << 24) | (gi << 12) | gj;
          }
        }
      }
      rqv = max(rqv, __shfl_xor(rqv, 1)); rqv = max(rqv, __shfl_xor(rqv, 2));
      rqv = max(rqv, __shfl_xor(rqv, 4)); rqv = max(rqv, __shfl_xor(rqv, 8));
      rpv = max(rpv, __shfl_xor(rpv, 1)); rpv = max(rpv, __shfl_xor(rpv, 2));
      rpv = max(rpv, __shfl_xor(rpv, 4)); rpv = max(rpv, __shfl_xor(rpv, 8));
      if (mlane == 0) {
        if (rqv >= 0) atomicMax(&smq[li], rqv);
        if (rpv >= 0) atomicMax(&smp[li], rpv);
      }
    }
  }
#pragma unroll
  for (int nj = 0; nj < 4; ++nj) {
    int u = cqv[nj];
    u = max(u, __shfl_xor(u, 16)); u = max(u, __shfl_xor(u, 32));
    if (qd == 0 && u >= 0) atomicMax(&scq[wn * 64 + nj * 16 + mlane], u);
  }
  __syncthreads();
  if (tid < 128) {
    if (smq[tid] >= 0) atomicMax(&q[(size_t)b * N_ + i0 + tid], smq[tid]);
    if (smp[tid] >= 0) atomicMax(&p[(size_t)b * N_ + i0 + tid], smp[tid]);
    if (scq[tid] >= 0) atomicMax(&q[(size_t)b * N_ + j0 + tid], scq[tid]);
  }
}

// ---------------------------------------------------------------------------
// Exact fp32-FMA + fp64-compare recheck of borderline pairs (round-0 logic).
__global__ __launch_bounds__(256) void fixup_kernel(const float* __restrict__ x,
                                                    const float* __restrict__ sq,
                                                    const int* __restrict__ mlist,
                                                    const int* __restrict__ mcnt,
                                                    int* __restrict__ p, int* __restrict__ q) {
  const int nw = gridDim.x * 4;
  const int gw = blockIdx.x * 4 + (threadIdx.x >> 6);
  const int lane = threadIdx.x & 63;
  const double THR = (double)22.63f;
  const double THR2 = THR * THR;
  int cnt = mcnt[0];
  if (cnt > MAXLIST) cnt = MAXLIST;
  for (int idx = gw; idx < cnt; idx += nw) {
    int pk = mlist[idx];
    int b = (pk >> 24) & 3, i = (pk >> 12) & 4095, j = pk & 4095;
    const float4 a = ((const float4*)(x + ((size_t)b * N_ + i) * F_))[lane];
    const float4 c = ((const float4*)(x + ((size_t)b * N_ + j) * F_))[lane];
    float s = a.x * c.x + a.y * c.y + a.z * c.z + a.w * c.w;
    for (int off = 32; off > 0; off >>= 1) s += __shfl_down(s, off);
    if (lane == 0) {
      double d2 = (double)sq[(size_t)b * N_ + i] + (double)sq[(size_t)b * N_ + j] - 2.0 * (double)s;
      if (d2 < THR2) {
        atomicMax(&q[(size_t)b * N_ + i], j);
        atomicMax(&q[(size_t)b * N_ + j], i);
        if (j < i) atomicMax(&p[(size_t)b * N_ + i], j);
      }
    }
  }
}

// ---------------------------------------------------------------------------
// Per-batch cluster kernel: root-chase p via pointer doubling, rank roots,
// labels[j] = rank[root(q(j))] -> lab (global); histogram + compact present
// labels ascending -> labs, Msz, Karr.
__global__ __launch_bounds__(1024) void cluster_kernel(const int* __restrict__ p,
                                                       const int* __restrict__ q,
                                                       int* __restrict__ lab,
                                                       int* __restrict__ Karr, int* __restrict__ labs,
                                                       int* __restrict__ Msz) {
  const int b = blockIdx.x, tid = threadIdx.x;
  __shared__ int A[N_ + 1], Bb[N_], labS[N_];
  __shared__ int waveOff[17];
  __shared__ int runBase;

  for (int k = tid; k < N_; k += 1024) {
    int pi = p[(size_t)b * N_ + k];
    A[k] = (pi < 0) ? k : pi;
  }
  __syncthreads();
  int* src = A; int* dst = Bb;
  for (int it = 0; it < 12; ++it) {
    for (int k = tid; k < N_; k += 1024) dst[k] = src[src[k]];
    __syncthreads();
    int* t = src; src = dst; dst = t;
  }
  if (tid == 0) runBase = 0;
  __syncthreads();
  for (int base = 0; base < N_; base += 1024) {
    int i = base + tid;
    bool isR = (src[i] == i);
    unsigned long long bal = __ballot(isR);
    int lane = tid & 63, wid = tid >> 6;
    if (lane == 0) waveOff[wid] = __popcll(bal);
    __syncthreads();
    if (tid == 0) {
      int s = runBase;
      for (int w = 0; w < 16; ++w) { int t2 = waveOff[w]; waveOff[w] = s; s += t2; }
      waveOff[16] = s;
    }
    __syncthreads();
    int incl = __popcll(bal & (~0ull >> (63 - lane)));
    dst[i] = waveOff[wid] + incl;
    __syncthreads();
    if (tid == 0) runBase = waveOff[16];
    __syncthreads();
  }
  for (int j = tid; j < N_; j += 1024) {
    int qq = q[(size_t)b * N_ + j];
    int lv = dst[src[qq]];
    labS[j] = lv;
    lab[(size_t)b * N_ + j] = lv;
  }
  __syncthreads();

  int* cnt = A;
  for (int k = tid; k <= N_; k += 1024) cnt[k] = 0;
  __syncthreads();
  for (int j = tid; j < N_; j += 1024) atomicAdd(&cnt[labS[j]], 1);
  __syncthreads();
  if (tid == 0) runBase = 0;
  __syncthreads();
  for (int base = 1; base <= N_; base += 1024) {
    int c = base + tid;
    bool m = (cnt[c] > 0);
    unsigned long long bal = __ballot(m);
    int lane = tid & 63, wid = tid >> 6;
    if (lane == 0) waveOff[wid] = __popcll(bal);
    __syncthreads();
    if (tid == 0) {
      int s = runBase;
      for (int w = 0; w < 16; ++w) { int t2 = waveOff[w]; waveOff[w] = s; s += t2; }
      waveOff[16] = s;
    }
    __syncthreads();
    if (m) {
      int pos = waveOff[wid] + __popcll(bal & ((1ull << lane) - 1));
      labs[(size_t)b * N_ + pos] = c;
      Msz[(size_t)b * N_ + pos] = cnt[c];
    }
    __syncthreads();
    if (tid == 0) runBase = waveOff[16];
    __syncthreads();
  }
  if (tid == 0) Karr[b] = runBase;
}

// ---------------------------------------------------------------------------
// MT19937 selection stream, wave-parallel (64 lanes). Msz preloaded to LDS in
// chunks. Bit-exact numpy RandomState(0).choice(M, 80, replace=True).
__device__ inline void mt_regen(unsigned* mt, unsigned* raw, int lane) {
  const int ph_s[3] = {0, 227, 454};
  const int ph_e[3] = {227, 454, 624};
#pragma unroll
  for (int ph = 0; ph < 3; ++ph) {
    const int s = ph_s[ph], e = ph_e[ph];
    unsigned aReg[4], bReg[4];
    const int niter = (e - s + 63) >> 6;
    for (int it = 0; it < niter; ++it) {
      int i = s + it * 64 + lane;
      if (i < e) { aReg[it] = mt[i]; bReg[it] = mt[(i + 1) % 624]; }
    }
    __syncthreads();
    for (int it = 0; it < niter; ++it) {
      int i = s + it * 64 + lane;
      if (i < e) {
        unsigned y = (aReg[it] & 0x80000000u) | (bReg[it] & 0x7fffffffu);
        mt[i] = mt[(i + 397) % 624] ^ (y >> 1) ^ ((y & 1u) ? 0x9908b0dfu : 0u);
      }
    }
    __syncthreads();
  }
  for (int it = 0; it < 10; ++it) {
    int i = it * 64 + lane;
    if (i < 624) {
      unsigned y = mt[i];
      y ^= y >> 11; y ^= (y << 7) & 0x9d2c5680u; y ^= (y << 15) & 0xefc60000u; y ^= y >> 18;
      raw[i] = y;
    }
  }
  __syncthreads();
}

__global__ __launch_bounds__(64) void rngsel_kernel(const int* __restrict__ Karr,
                                                    const int* __restrict__ Msz,
                                                    int* __restrict__ sel, int* __restrict__ meta,
                                                    int* __restrict__ totK) {
  __shared__ unsigned mt[624];
  __shared__ unsigned raw[624];
  __shared__ int mszS[2048];
  const int lane = threadIdx.x;
  if (lane == 0) {  // numpy init_genrand(0) — strictly serial recurrence
    mt[0] = 0u;
    for (int i = 1; i < 624; ++i) mt[i] = 1812433253u * (mt[i - 1] ^ (mt[i - 1] >> 30)) + (unsigned)i;
  }
  __syncthreads();
  int pos = 624;  // force twist on first draw (numpy mti==N after seed)
  int cid = 0;
  for (int b = 0; b < B_; ++b) {
    const int Kb = Karr[b];
    for (int k0 = 0; k0 < Kb; k0 += 2048) {
      const int nk = min(2048, Kb - k0);
      for (int i = lane; i < nk; i += 64) mszS[i] = Msz[(size_t)b * N_ + k0 + i];
      for (int kk = 0; kk < nk; ++kk) {
        const int M = mszS[kk];
        if (lane == 0) meta[cid] = (b << 16) | (k0 + kk);
        if (M <= 1) {
          sel[cid * DS + lane] = 0;
          if (lane < DS - 64) sel[cid * DS + 64 + lane] = 0;
        } else {
          const unsigned rng = (unsigned)(M - 1);
          unsigned mask = rng;
          mask |= mask >> 1; mask |= mask >> 2; mask |= mask >> 4; mask |= mask >> 8; mask |= mask >> 16;
          int acc = 0;
          while (acc < DS) {
            if (pos == 624) { mt_regen(mt, raw, lane); pos = 0; }
            int take = 624 - pos; if (take > 64) take = 64;
            unsigned v = 0xFFFFFFFFu;
            bool ok = false;
            if (lane < take) { v = raw[pos + lane] & mask; ok = (v <= rng); }
            unsigned long long bal = __ballot(ok);
            int pre = __popcll(bal & ((1ull << lane) - 1ull));
            int tot = __popcll(bal);
            if (ok && acc + pre < DS) sel[cid * DS + acc + pre] = (int)v;
            if (acc + tot >= DS) {
              int need = DS - acc;
              bool win = ok && (pre + 1 == need);
              unsigned long long wb = __ballot(win);
              pos += __ffsll(wb);  // lane index +1 = draws consumed from chunk
              acc = DS;
            } else {
              pos += take;
              acc += tot;
            }
          }
        }
        ++cid;
      }
    }
  }
  if (lane == 0) totK[0] = cid;
}

// ---------------------------------------------------------------------------
// Parallel classify: one block per cluster (grid-stride). Membership bitmask
// rebuilt from lab; rank-select; PointNet-lite; per-cluster loss.
__global__ __launch_bounds__(256) void classify_par_kernel(
    const float* __restrict__ points, const float* __restrict__ W1, const float* __restrict__ b1,
    const float* __restrict__ W2, const float* __restrict__ b2,
    const float* __restrict__ W3, const float* __restrict__ b3,
    const int* __restrict__ lab, const int* __restrict__ labs,
    const int* __restrict__ sel, const int* __restrict__ meta, const int* __restrict__ totK,
    float* __restrict__ lossArr) {
  __shared__ unsigned wordsS[128];
  __shared__ int prefS[128];
  __shared__ float pts[DS][3];
  __shared__ float h1[DS][64];
  __shared__ float W2s[64][128];
  __shared__ float gmax[128];
  const int tid = threadIdx.x;
  int T = totK[0]; if (T > MAXC) T = MAXC;
  for (int k = tid; k < 64 * 128; k += 256) W2s[k >> 7][k & 127] = W2[k];

  for (int cid = blockIdx.x; cid < T; cid += gridDim.x) {
    const int mv = meta[cid];
    const int b = mv >> 16, k = mv & 0xFFFF;
    const int c = labs[(size_t)b * N_ + k];
    if (tid < 128) {
      unsigned wbits = 0;
      const int* lb = lab + (size_t)b * N_ + tid * 32;
      for (int s = 0; s < 32; ++s) wbits |= (lb[s] == c) ? (1u << s) : 0u;
      wordsS[tid] = wbits;
    }
    __syncthreads();
    if (tid == 0) {
      int s = 0;
      for (int w2 = 0; w2 < 128; ++w2) { prefS[w2] = s; s += __popc(wordsS[w2]); }
    }
    __syncthreads();
    if (tid < DS) {
      int r = sel[cid * DS + tid];
      int lo = 0, hi = 127;
      while (lo < hi) { int mid = (lo + hi + 1) >> 1; if (prefS[mid] <= r) lo = mid; else hi = mid - 1; }
      int rem = r - prefS[lo];
      unsigned wbits = wordsS[lo];
      int j = lo * 32;
      for (;;) {
        int bpos = __ffs(wbits) - 1;
        if (rem == 0) { j += bpos; break; }
        wbits &= wbits - 1; --rem;
      }
      pts[tid][0] = points[((size_t)b * N_ + j) * 3 + 0];
      pts[tid][1] = points[((size_t)b * N_ + j) * 3 + 1];
      pts[tid][2] = points[((size_t)b * N_ + j) * 3 + 2];
    }
    __syncthreads();
    for (int o = tid; o < DS * 64; o += 256) {
      int r = o >> 6, cc = o & 63;
      float v = pts[r][0] * W1[cc] + pts[r][1] * W1[64 + cc] + pts[r][2] * W1[128 + cc] + b1[cc];
      h1[r][cc] = fmaxf(v, 0.f);
    }
    __syncthreads();
    {
      const int cc = tid & 127, half = tid >> 7;
      const float b2c = b2[cc];
      float m = -1e30f;
      for (int r = half * 40; r < half * 40 + 40; ++r) {
        float a0 = 0.f, a1 = 0.f, a2 = 0.f, a3 = 0.f;
#pragma unroll
        for (int kk = 0; kk < 64; kk += 4) {
          a0 += h1[r][kk + 0] * W2s[kk + 0][cc];
          a1 += h1[r][kk + 1] * W2s[kk + 1][cc];
          a2 += h1[r][kk + 2] * W2s[kk + 2][cc];
          a3 += h1[r][kk + 3] * W2s[kk + 3][cc];
        }
        float acc = ((a0 + a1) + (a2 + a3)) + b2c;
        m = fmaxf(m, fmaxf(acc, 0.f));
      }
      if (half == 0) gmax[cc] = m;
      __syncthreads();
      if (half == 1) gmax[cc] = fmaxf(gmax[cc], m);
    }
    __syncthreads();
    if (tid == 0) {
      float l0 = b3[0], l1 = b3[1];
      for (int cc = 0; cc < 128; ++cc) { l0 += gmax[cc] * W3[cc * 2 + 0]; l1 += gmax[cc] * W3[cc * 2 + 1]; }
      float mx = fmaxf(l0, l1);
      float e0 = expf(l0 - mx), e1 = expf(l1 - mx);
      float p1 = e1 / (e0 + e1);
      if (isnan(p1)) p1 = 0.f;
      lossArr[cid] = fminf(-logf(p1), 100.f);
    }
    __syncthreads();
  }
}

// ---------------------------------------------------------------------------
__global__ __launch_bounds__(256) void reduce_kernel(const float* __restrict__ lossArr,
                                                     const int* __restrict__ meta,
                                                     const int* __restrict__ totK,
                                                     const int* __restrict__ Karr,
                                                     float* __restrict__ out) {
  __shared__ float accB[4];
  const int tid = threadIdx.x;
  if (tid < 4) accB[tid] = 0.f;
  __syncthreads();
  int T = totK[0]; if (T > MAXC) T = MAXC;
  float local[4] = {0.f, 0.f, 0.f, 0.f};
  for (int cid = tid; cid < T; cid += 256) local[meta[cid] >> 16] += lossArr[cid];
  for (int b = 0; b < 4; ++b) {
    float v = local[b];
    for (int off = 32; off > 0; off >>= 1) v += __shfl_down(v, off);
    if ((tid & 63) == 0) atomicAdd(&accB[b], v);
  }
  __syncthreads();
  if (tid == 0) {
    float tot = 0.f;
    for (int b = 0; b < 4; ++b) tot += accB[b] / (float)Karr[b];
    out[0] = tot;
  }
}

// ---------------------------------------------------------------------------
extern "C" void kernel_launch(void* const* d_in, const int* in_sizes, int n_in,
                              void* d_out, int out_size, void* d_ws, size_t ws_size,
                              hipStream_t stream) {
  const float* x      = (const float*)d_in[0];
  const float* points = (const float*)d_in[1];
  const float* W1 = (const float*)d_in[2];
  const float* b1 = (const float*)d_in[3];
  const float* W2 = (const float*)d_in[4];
  const float* b2 = (const float*)d_in[5];
  const float* W3 = (const float*)d_in[6];
  const float* b3 = (const float*)d_in[7];
  float* out = (float*)d_out;

  char* wsb = (char*)d_ws;
  size_t off = 0;
  auto carve = [&](size_t bytes) -> void* {
    void* r = wsb + off;
    off += (bytes + 255) & ~(size_t)255;
    return r;
  };
  float* sq      = (float*)carve((size_t)B_ * N_ * 4);
  int* p         = (int*)carve((size_t)B_ * N_ * 4);
  int* q         = (int*)carve((size_t)B_ * N_ * 4);
  int* lab       = (int*)carve((size_t)B_ * N_ * 4);
  int* labs      = (int*)carve((size_t)B_ * N_ * 4);
  int* Msz       = (int*)carve((size_t)B_ * N_ * 4);
  int* Karr      = (int*)carve(256);
  int* mcnt      = (int*)carve(256);
  int* totK      = (int*)carve(256);
  f16* Xhi       = (f16*)carve((size_t)B_ * N_ * F_ * 2);
  int* mlist     = (int*)carve((size_t)MAXLIST * 4);
  int* sel       = (int*)carve((size_t)MAXC * DS * 4);
  int* meta      = (int*)carve((size_t)MAXC * 4);
  float* lossArr = (float*)carve((size_t)MAXC * 4);
  (void)ws_size;

  hipLaunchKernelGGL(pre_kernel, dim3(B_ * N_ * F_ / 1024), dim3(256), 0, stream,
                     x, sq, Xhi, p, q, mcnt);
  hipLaunchKernelGGL(distmf_kernel, dim3(528 * B_), dim3(256), 0, stream,
                     Xhi, sq, p, q, mlist, mcnt);
  hipLaunchKernelGGL(fixup_kernel, dim3(512), dim3(256), 0, stream, x, sq, mlist, mcnt, p, q);
  hipLaunchKernelGGL(cluster_kernel, dim3(B_), dim3(1024), 0, stream,
                     p, q, lab, Karr, labs, Msz);
  hipLaunchKernelGGL(rngsel_kernel, dim3(1), dim3(64), 0, stream, Karr, Msz, sel, meta, totK);
  hipLaunchKernelGGL(classify_par_kernel, dim3(512), dim3(256), 0, stream,
                     points, W1, b1, W2, b2, W3, b3, lab, labs, sel, meta, totK, lossArr);
  hipLaunchKernelGGL(reduce_kernel, dim3(1), dim3(256), 0, stream,
                     lossArr, meta, totK, Karr, out);
}

// Round 8
// 264.961 us; speedup vs baseline: 4.2997x; 4.2997x over previous
//
#include <hip/hip_runtime.h>
#include <hip/hip_bf16.h>
#include <math.h>
#include <stdint.h>

// Problem constants (fixed by setup_inputs)
constexpr int B_ = 4, N_ = 4096, F_ = 256;
constexpr int DS = 80;
constexpr int MAXLIST = 1 << 19;
constexpr int MAXC = 16384;  // hard bound: K_b <= N, B=4

typedef _Float16 f16;
typedef f16 f16x4 __attribute__((ext_vector_type(4)));
typedef f16 f16x8 __attribute__((ext_vector_type(8)));
typedef float f32x4 __attribute__((ext_vector_type(4)));

// async global->LDS, 16B per lane; LDS dest is wave-uniform base + lane*16
#define GLD16(gp, lp)                                                                      \
  __builtin_amdgcn_global_load_lds(                                                        \
      reinterpret_cast<const __attribute__((address_space(1))) unsigned int*>(             \
          reinterpret_cast<uintptr_t>(gp)),                                                \
      reinterpret_cast<__attribute__((address_space(3))) unsigned int*>(                   \
          reinterpret_cast<uintptr_t>(lp)),                                                \
      16, 0, 0)

// ---------------------------------------------------------------------------
// Fused: fp32->f16 convert (hi only) + row sumsq + p/q init. Block = 4 rows.
__global__ __launch_bounds__(256) void pre_kernel(const float* __restrict__ x,
                                                  float* __restrict__ sq,
                                                  f16* __restrict__ xhi,
                                                  int* __restrict__ p, int* __restrict__ q,
                                                  int* __restrict__ mcnt) {
  const int blk = blockIdx.x, tid = threadIdx.x;
  const int i = blk * 256 + tid;  // float4 index
  float4 v = ((const float4*)x)[i];
  f16x4 h;
  h[0] = (f16)v.x; h[1] = (f16)v.y; h[2] = (f16)v.z; h[3] = (f16)v.w;
  ((f16x4*)xhi)[i] = h;
  float s = v.x * v.x + v.y * v.y + v.z * v.z + v.w * v.w;
  for (int off = 32; off > 0; off >>= 1) s += __shfl_down(s, off);
  const int lane = tid & 63, w = tid >> 6;
  if (lane == 0) sq[blk * 4 + w] = s;  // one wave == one 256-float row
  if (blk < 64) {
    int idx = blk * 256 + tid;
    p[idx] = -1; q[idx] = -1;
    if (idx == 0) mcnt[0] = 0;
  }
}

// ---------------------------------------------------------------------------
// MFMA hi-only pairwise-distance kernel. 128x128 lower-triangle tiles,
// XCD-pinned batches (b = bid&3). Full double-buffer, prefetch-before-MFMA,
// one barrier per step, 16 MFMAs/step, single acc[16].
// Borderline pairs (|d2-thr2|<EPS) are compacted with ONE global atomic per
// BLOCK (count -> shuffle-scan -> reserve -> re-derive & write). Per-pair
// same-address atomicAdd was the R6/R7 regression: ~10 ns/op serialized chain.
__global__ __launch_bounds__(256, 2) void distmf_kernel(
    const f16* __restrict__ xhi,
    const float* __restrict__ sq, int* __restrict__ p, int* __restrict__ q,
    int* __restrict__ mlist, int* __restrict__ mcnt) {
  const int bid = blockIdx.x;
  const int b = bid & 3;          // XCD k (bid%8) -> fixed batch (k&3): 2MB/XCD L2-resident
  const int t = bid >> 2;
  int ti = (int)((sqrtf(8.f * (float)t + 1.f) - 1.f) * 0.5f);
  while ((ti + 1) * (ti + 2) / 2 <= t) ++ti;
  while (ti * (ti + 1) / 2 > t) --ti;
  const int tj = t - ti * (ti + 1) / 2;
  const int i0 = ti * 128, j0 = tj * 128;

  __shared__ __align__(16) f16 Ah[2][4096], Bh[2][4096];
  __shared__ float sqi_s[128], sqj_s[128];
  __shared__ int smq[128], smp[128], scq[128];
  __shared__ int wTot[4];
  __shared__ int blkBase;

  const int tid = threadIdx.x;
  const int w = tid >> 6, lane = tid & 63;
  const size_t bOff = (size_t)b * N_ * F_;
  const f16* Ahg = xhi + bOff + (size_t)i0 * F_;
  const f16* Bhg = xhi + bOff + (size_t)j0 * F_;

  // staging: chunk g = part*256 + w*64 + lane; kq = g>>7, row = g&127
  const int g1 = w * 64 + lane, g2 = 256 + g1;
  const size_t o1 = (size_t)(g1 & 127) * F_ + (size_t)(g1 >> 7) * 8;
  const size_t o2 = (size_t)(g2 & 127) * F_ + (size_t)(g2 >> 7) * 8;
  const int d1 = w * 64 * 8;
  const int d2e = d1 + 2048;

  // prologue: stage step 0 into buf 0
  GLD16(Ahg + o1, &Ah[0][d1]);
  GLD16(Ahg + o2, &Ah[0][d2e]);
  GLD16(Bhg + o1, &Bh[0][d1]);
  GLD16(Bhg + o2, &Bh[0][d2e]);

  if (tid < 128) {
    sqi_s[tid] = sq[(size_t)b * N_ + i0 + tid];
    sqj_s[tid] = sq[(size_t)b * N_ + j0 + tid];
    smq[tid] = -1; smp[tid] = -1; scq[tid] = -1;
  }

  f32x4 acc[16];
  const f32x4 zero4 = {0.f, 0.f, 0.f, 0.f};
#pragma unroll
  for (int i2 = 0; i2 < 16; ++i2) acc[i2] = zero4;

  const int wm = w >> 1, wn = w & 1;
  const int mlane = lane & 15, qd = lane >> 4;
  __syncthreads();

#pragma unroll
  for (int step = 0; step < 8; ++step) {
    const int cur = step & 1, nxt = cur ^ 1;
    f16x8 ah[4], bh[4];
#pragma unroll
    for (int mi = 0; mi < 4; ++mi) {
      int ch = (qd * 128 + wm * 64 + mi * 16 + mlane) * 8;
      ah[mi] = *(const f16x8*)&Ah[cur][ch];
    }
#pragma unroll
    for (int nj = 0; nj < 4; ++nj) {
      int ch = (qd * 128 + wn * 64 + nj * 16 + mlane) * 8;
      bh[nj] = *(const f16x8*)&Bh[cur][ch];
    }
    if (step < 7) {
      const size_t k0 = (size_t)(step + 1) * 32;
      GLD16(Ahg + o1 + k0, &Ah[nxt][d1]);
      GLD16(Ahg + o2 + k0, &Ah[nxt][d2e]);
      GLD16(Bhg + o1 + k0, &Bh[nxt][d1]);
      GLD16(Bhg + o2 + k0, &Bh[nxt][d2e]);
    }
#pragma unroll
    for (int mi = 0; mi < 4; ++mi)
#pragma unroll
      for (int nj = 0; nj < 4; ++nj)
        acc[mi * 4 + nj] = __builtin_amdgcn_mfma_f32_16x16x32_f16(ah[mi], bh[nj], acc[mi * 4 + nj], 0, 0, 0);
    __syncthreads();
  }

  // Epilogue pass A: p/q max updates + borderline COUNT (no atomics per pair).
  const float THR2F = (float)((double)22.63f * (double)22.63f);
  const float EPS = 0.15f;  // hi-only d2 error std ~1.1e-2 -> ~13 sigma
  const float thr_lo = THR2F - EPS, thr_hi = THR2F + EPS;
  int nb = 0;
  int cqv[4] = {-1, -1, -1, -1};
#pragma unroll
  for (int mi = 0; mi < 4; ++mi) {
#pragma unroll
    for (int e = 0; e < 4; ++e) {
      const int li = wm * 64 + mi * 16 + qd * 4 + e;
      const int gi = i0 + li;
      const float sqi = sqi_s[li];
      int rqv = -1, rpv = -1;
#pragma unroll
      for (int nj = 0; nj < 4; ++nj) {
        const int idx = mi * 4 + nj;
        const int lj = wn * 64 + nj * 16 + mlane;
        const int gj = j0 + lj;
        float d2 = sqi + sqj_s[lj] - 2.0f * acc[idx][e];
        if (gj <= gi) {
          if (d2 < thr_lo) {
            rqv = max(rqv, gj);
            if (gj < gi) rpv = max(rpv, gj);
            cqv[nj] = max(cqv[nj], gi);
          } else if (d2 < thr_hi) {
            ++nb;
          }
        }
      }
      rqv = max(rqv, __shfl_xor(rqv, 1)); rqv = max(rqv, __shfl_xor(rqv, 2));
      rqv = max(rqv, __shfl_xor(rqv, 4)); rqv = max(rqv, __shfl_xor(rqv, 8));
      rpv = max(rpv, __shfl_xor(rpv, 1)); rpv = max(rpv, __shfl_xor(rpv, 2));
      rpv = max(rpv, __shfl_xor(rpv, 4)); rpv = max(rpv, __shfl_xor(rpv, 8));
      if (mlane == 0) {
        if (rqv >= 0) atomicMax(&smq[li], rqv);
        if (rpv >= 0) atomicMax(&smp[li], rpv);
      }
    }
  }
#pragma unroll
  for (int nj = 0; nj < 4; ++nj) {
    int u = cqv[nj];
    u = max(u, __shfl_xor(u, 16)); u = max(u, __shfl_xor(u, 32));
    if (qd == 0 && u >= 0) atomicMax(&scq[wn * 64 + nj * 16 + mlane], u);
  }

  // Reserve mlist slice: shuffle inclusive-scan within wave, LDS across waves,
  // ONE atomicAdd per block.
  int scan = nb;
#pragma unroll
  for (int d = 1; d < 64; d <<= 1) {
    int t2 = __shfl_up(scan, d);
    if (lane >= d) scan += t2;
  }
  if (lane == 63) wTot[w] = scan;
  __syncthreads();
  if (tid == 0) {
    int s0 = wTot[0], s1 = wTot[1], s2 = wTot[2], s3 = wTot[3];
    int tot = s0 + s1 + s2 + s3;
    wTot[0] = 0; wTot[1] = s0; wTot[2] = s0 + s1; wTot[3] = s0 + s1 + s2;
    blkBase = (tot > 0) ? atomicAdd(mcnt, tot) : 0;
  }
  __syncthreads();
  int myoff = blkBase + wTot[w] + (scan - nb);

  // Pass B: re-derive borderline pairs (deterministic fp32) and write them.
  if (nb > 0) {
#pragma unroll
    for (int mi = 0; mi < 4; ++mi) {
#pragma unroll
      for (int e = 0; e < 4; ++e) {
        const int li = wm * 64 + mi * 16 + qd * 4 + e;
        const int gi = i0 + li;
        const float sqi = sqi_s[li];
#pragma unroll
        for (int nj = 0; nj < 4; ++nj) {
          const int idx = mi * 4 + nj;
          const int lj = wn * 64 + nj * 16 + mlane;
          const int gj = j0 + lj;
          float d2 = sqi + sqj_s[lj] - 2.0f * acc[idx][e];
          if (gj <= gi && d2 >= thr_lo && d2 < thr_hi) {
            if (myoff < MAXLIST) mlist[myoff] = (b << 24) | (gi << 12) | gj;
            ++myoff;
          }
        }
      }
    }
  }

  __syncthreads();
  if (tid < 128) {
    if (smq[tid] >= 0) atomicMax(&q[(size_t)b * N_ + i0 + tid], smq[tid]);
    if (smp[tid] >= 0) atomicMax(&p[(size_t)b * N_ + i0 + tid], smp[tid]);
    if (scq[tid] >= 0) atomicMax(&q[(size_t)b * N_ + j0 + tid], scq[tid]);
  }
}

// ---------------------------------------------------------------------------
// Exact fp32-FMA + fp64-compare recheck of borderline pairs (round-0 logic).
__global__ __launch_bounds__(256) void fixup_kernel(const float* __restrict__ x,
                                                    const float* __restrict__ sq,
                                                    const int* __restrict__ mlist,
                                                    const int* __restrict__ mcnt,
                                                    int* __restrict__ p, int* __restrict__ q) {
  const int nw = gridDim.x * 4;
  const int gw = blockIdx.x * 4 + (threadIdx.x >> 6);
  const int lane = threadIdx.x & 63;
  const double THR = (double)22.63f;
  const double THR2 = THR * THR;
  int cnt = mcnt[0];
  if (cnt > MAXLIST) cnt = MAXLIST;
  for (int idx = gw; idx < cnt; idx += nw) {
    int pk = mlist[idx];
    int b = (pk >> 24) & 3, i = (pk >> 12) & 4095, j = pk & 4095;
    const float4 a = ((const float4*)(x + ((size_t)b * N_ + i) * F_))[lane];
    const float4 c = ((const float4*)(x + ((size_t)b * N_ + j) * F_))[lane];
    float s = a.x * c.x + a.y * c.y + a.z * c.z + a.w * c.w;
    for (int off = 32; off > 0; off >>= 1) s += __shfl_down(s, off);
    if (lane == 0) {
      double d2 = (double)sq[(size_t)b * N_ + i] + (double)sq[(size_t)b * N_ + j] - 2.0 * (double)s;
      if (d2 < THR2) {
        atomicMax(&q[(size_t)b * N_ + i], j);
        atomicMax(&q[(size_t)b * N_ + j], i);
        if (j < i) atomicMax(&p[(size_t)b * N_ + i], j);
      }
    }
  }
}

// ---------------------------------------------------------------------------
// Per-batch cluster kernel: root-chase p via pointer doubling, rank roots,
// labels[j] = rank[root(q(j))] -> lab (global); histogram + compact present
// labels ascending -> labs, Msz, Karr.
__global__ __launch_bounds__(1024) void cluster_kernel(const int* __restrict__ p,
                                                       const int* __restrict__ q,
                                                       int* __restrict__ lab,
                                                       int* __restrict__ Karr, int* __restrict__ labs,
                                                       int* __restrict__ Msz) {
  const int b = blockIdx.x, tid = threadIdx.x;
  __shared__ int A[N_ + 1], Bb[N_], labS[N_];
  __shared__ int waveOff[17];
  __shared__ int runBase;

  for (int k = tid; k < N_; k += 1024) {
    int pi = p[(size_t)b * N_ + k];
    A[k] = (pi < 0) ? k : pi;
  }
  __syncthreads();
  int* src = A; int* dst = Bb;
  for (int it = 0; it < 12; ++it) {
    for (int k = tid; k < N_; k += 1024) dst[k] = src[src[k]];
    __syncthreads();
    int* t = src; src = dst; dst = t;
  }
  if (tid == 0) runBase = 0;
  __syncthreads();
  for (int base = 0; base < N_; base += 1024) {
    int i = base + tid;
    bool isR = (src[i] == i);
    unsigned long long bal = __ballot(isR);
    int lane = tid & 63, wid = tid >> 6;
    if (lane == 0) waveOff[wid] = __popcll(bal);
    __syncthreads();
    if (tid == 0) {
      int s = runBase;
      for (int w = 0; w < 16; ++w) { int t2 = waveOff[w]; waveOff[w] = s; s += t2; }
      waveOff[16] = s;
    }
    __syncthreads();
    int incl = __popcll(bal & (~0ull >> (63 - lane)));
    dst[i] = waveOff[wid] + incl;
    __syncthreads();
    if (tid == 0) runBase = waveOff[16];
    __syncthreads();
  }
  for (int j = tid; j < N_; j += 1024) {
    int qq = q[(size_t)b * N_ + j];
    int lv = dst[src[qq]];
    labS[j] = lv;
    lab[(size_t)b * N_ + j] = lv;
  }
  __syncthreads();

  int* cnt = A;
  for (int k = tid; k <= N_; k += 1024) cnt[k] = 0;
  __syncthreads();
  for (int j = tid; j < N_; j += 1024) atomicAdd(&cnt[labS[j]], 1);
  __syncthreads();
  if (tid == 0) runBase = 0;
  __syncthreads();
  for (int base = 1; base <= N_; base += 1024) {
    int c = base + tid;
    bool m = (cnt[c] > 0);
    unsigned long long bal = __ballot(m);
    int lane = tid & 63, wid = tid >> 6;
    if (lane == 0) waveOff[wid] = __popcll(bal);
    __syncthreads();
    if (tid == 0) {
      int s = runBase;
      for (int w = 0; w < 16; ++w) { int t2 = waveOff[w]; waveOff[w] = s; s += t2; }
      waveOff[16] = s;
    }
    __syncthreads();
    if (m) {
      int pos = waveOff[wid] + __popcll(bal & ((1ull << lane) - 1));
      labs[(size_t)b * N_ + pos] = c;
      Msz[(size_t)b * N_ + pos] = cnt[c];
    }
    __syncthreads();
    if (tid == 0) runBase = waveOff[16];
    __syncthreads();
  }
  if (tid == 0) Karr[b] = runBase;
}

// ---------------------------------------------------------------------------
// MT19937 selection stream, wave-parallel (64 lanes). Msz preloaded to LDS in
// chunks. Bit-exact numpy RandomState(0).choice(M, 80, replace=True).
__device__ inline void mt_regen(unsigned* mt, unsigned* raw, int lane) {
  const int ph_s[3] = {0, 227, 454};
  const int ph_e[3] = {227, 454, 624};
#pragma unroll
  for (int ph = 0; ph < 3; ++ph) {
    const int s = ph_s[ph], e = ph_e[ph];
    unsigned aReg[4], bReg[4];
    const int niter = (e - s + 63) >> 6;
    for (int it = 0; it < niter; ++it) {
      int i = s + it * 64 + lane;
      if (i < e) { aReg[it] = mt[i]; bReg[it] = mt[(i + 1) % 624]; }
    }
    __syncthreads();
    for (int it = 0; it < niter; ++it) {
      int i = s + it * 64 + lane;
      if (i < e) {
        unsigned y = (aReg[it] & 0x80000000u) | (bReg[it] & 0x7fffffffu);
        mt[i] = mt[(i + 397) % 624] ^ (y >> 1) ^ ((y & 1u) ? 0x9908b0dfu : 0u);
      }
    }
    __syncthreads();
  }
  for (int it = 0; it < 10; ++it) {
    int i = it * 64 + lane;
    if (i < 624) {
      unsigned y = mt[i];
      y ^= y >> 11; y ^= (y << 7) & 0x9d2c5680u; y ^= (y << 15) & 0xefc60000u; y ^= y >> 18;
      raw[i] = y;
    }
  }
  __syncthreads();
}

__global__ __launch_bounds__(64) void rngsel_kernel(const int* __restrict__ Karr,
                                                    const int* __restrict__ Msz,
                                                    int* __restrict__ sel, int* __restrict__ meta,
                                                    int* __restrict__ totK) {
  __shared__ unsigned mt[624];
  __shared__ unsigned raw[624];
  __shared__ int mszS[2048];
  const int lane = threadIdx.x;
  if (lane == 0) {  // numpy init_genrand(0) — strictly serial recurrence
    mt[0] = 0u;
    for (int i = 1; i < 624; ++i) mt[i] = 1812433253u * (mt[i - 1] ^ (mt[i - 1] >> 30)) + (unsigned)i;
  }
  __syncthreads();
  int pos = 624;  // force twist on first draw (numpy mti==N after seed)
  int cid = 0;
  for (int b = 0; b < B_; ++b) {
    const int Kb = Karr[b];
    for (int k0 = 0; k0 < Kb; k0 += 2048) {
      const int nk = min(2048, Kb - k0);
      for (int i = lane; i < nk; i += 64) mszS[i] = Msz[(size_t)b * N_ + k0 + i];
      for (int kk = 0; kk < nk; ++kk) {
        const int M = mszS[kk];
        if (lane == 0) meta[cid] = (b << 16) | (k0 + kk);
        if (M <= 1) {
          sel[cid * DS + lane] = 0;
          if (lane < DS - 64) sel[cid * DS + 64 + lane] = 0;
        } else {
          const unsigned rng = (unsigned)(M - 1);
          unsigned mask = rng;
          mask |= mask >> 1; mask |= mask >> 2; mask |= mask >> 4; mask |= mask >> 8; mask |= mask >> 16;
          int acc = 0;
          while (acc < DS) {
            if (pos == 624) { mt_regen(mt, raw, lane); pos = 0; }
            int take = 624 - pos; if (take > 64) take = 64;
            unsigned v = 0xFFFFFFFFu;
            bool ok = false;
            if (lane < take) { v = raw[pos + lane] & mask; ok = (v <= rng); }
            unsigned long long bal = __ballot(ok);
            int pre = __popcll(bal & ((1ull << lane) - 1ull));
            int tot = __popcll(bal);
            if (ok && acc + pre < DS) sel[cid * DS + acc + pre] = (int)v;
            if (acc + tot >= DS) {
              int need = DS - acc;
              bool win = ok && (pre + 1 == need);
              unsigned long long wb = __ballot(win);
              pos += __ffsll(wb);  // lane index +1 = draws consumed from chunk
              acc = DS;
            } else {
              pos += take;
              acc += tot;
            }
          }
        }
        ++cid;
      }
    }
  }
  if (lane == 0) totK[0] = cid;
}

// ---------------------------------------------------------------------------
// Parallel classify: one block per cluster (grid-stride). Membership bitmask
// rebuilt from lab; rank-select; PointNet-lite; per-cluster loss.
__global__ __launch_bounds__(256) void classify_par_kernel(
    const float* __restrict__ points, const float* __restrict__ W1, const float* __restrict__ b1,
    const float* __restrict__ W2, const float* __restrict__ b2,
    const float* __restrict__ W3, const float* __restrict__ b3,
    const int* __restrict__ lab, const int* __restrict__ labs,
    const int* __restrict__ sel, const int* __restrict__ meta, const int* __restrict__ totK,
    float* __restrict__ lossArr) {
  __shared__ unsigned wordsS[128];
  __shared__ int prefS[128];
  __shared__ float pts[DS][3];
  __shared__ float h1[DS][64];
  __shared__ float W2s[64][128];
  __shared__ float gmax[128];
  const int tid = threadIdx.x;
  int T = totK[0]; if (T > MAXC) T = MAXC;
  for (int k = tid; k < 64 * 128; k += 256) W2s[k >> 7][k & 127] = W2[k];

  for (int cid = blockIdx.x; cid < T; cid += gridDim.x) {
    const int mv = meta[cid];
    const int b = mv >> 16, k = mv & 0xFFFF;
    const int c = labs[(size_t)b * N_ + k];
    if (tid < 128) {
      unsigned wbits = 0;
      const int* lb = lab + (size_t)b * N_ + tid * 32;
      for (int s = 0; s < 32; ++s) wbits |= (lb[s] == c) ? (1u << s) : 0u;
      wordsS[tid] = wbits;
    }
    __syncthreads();
    if (tid == 0) {
      int s = 0;
      for (int w2 = 0; w2 < 128; ++w2) { prefS[w2] = s; s += __popc(wordsS[w2]); }
    }
    __syncthreads();
    if (tid < DS) {
      int r = sel[cid * DS + tid];
      int lo = 0, hi = 127;
      while (lo < hi) { int mid = (lo + hi + 1) >> 1; if (prefS[mid] <= r) lo = mid; else hi = mid - 1; }
      int rem = r - prefS[lo];
      unsigned wbits = wordsS[lo];
      int j = lo * 32;
      for (;;) {
        int bpos = __ffs(wbits) - 1;
        if (rem == 0) { j += bpos; break; }
        wbits &= wbits - 1; --rem;
      }
      pts[tid][0] = points[((size_t)b * N_ + j) * 3 + 0];
      pts[tid][1] = points[((size_t)b * N_ + j) * 3 + 1];
      pts[tid][2] = points[((size_t)b * N_ + j) * 3 + 2];
    }
    __syncthreads();
    for (int o = tid; o < DS * 64; o += 256) {
      int r = o >> 6, cc = o & 63;
      float v = pts[r][0] * W1[cc] + pts[r][1] * W1[64 + cc] + pts[r][2] * W1[128 + cc] + b1[cc];
      h1[r][cc] = fmaxf(v, 0.f);
    }
    __syncthreads();
    {
      const int cc = tid & 127, half = tid >> 7;
      const float b2c = b2[cc];
      float m = -1e30f;
      for (int r = half * 40; r < half * 40 + 40; ++r) {
        float a0 = 0.f, a1 = 0.f, a2 = 0.f, a3 = 0.f;
#pragma unroll
        for (int kk = 0; kk < 64; kk += 4) {
          a0 += h1[r][kk + 0] * W2s[kk + 0][cc];
          a1 += h1[r][kk + 1] * W2s[kk + 1][cc];
          a2 += h1[r][kk + 2] * W2s[kk + 2][cc];
          a3 += h1[r][kk + 3] * W2s[kk + 3][cc];
        }
        float acc = ((a0 + a1) + (a2 + a3)) + b2c;
        m = fmaxf(m, fmaxf(acc, 0.f));
      }
      if (half == 0) gmax[cc] = m;
      __syncthreads();
      if (half == 1) gmax[cc] = fmaxf(gmax[cc], m);
    }
    __syncthreads();
    if (tid == 0) {
      float l0 = b3[0], l1 = b3[1];
      for (int cc = 0; cc < 128; ++cc) { l0 += gmax[cc] * W3[cc * 2 + 0]; l1 += gmax[cc] * W3[cc * 2 + 1]; }
      float mx = fmaxf(l0, l1);
      float e0 = expf(l0 - mx), e1 = expf(l1 - mx);
      float p1 = e1 / (e0 + e1);
      if (isnan(p1)) p1 = 0.f;
      lossArr[cid] = fminf(-logf(p1), 100.f);
    }
    __syncthreads();
  }
}

// ---------------------------------------------------------------------------
__global__ __launch_bounds__(256) void reduce_kernel(const float* __restrict__ lossArr,
                                                     const int* __restrict__ meta,
                                                     const int* __restrict__ totK,
                                                     const int* __restrict__ Karr,
                                                     float* __restrict__ out) {
  __shared__ float accB[4];
  const int tid = threadIdx.x;
  if (tid < 4) accB[tid] = 0.f;
  __syncthreads();
  int T = totK[0]; if (T > MAXC) T = MAXC;
  float local[4] = {0.f, 0.f, 0.f, 0.f};
  for (int cid = tid; cid < T; cid += 256) local[meta[cid] >> 16] += lossArr[cid];
  for (int b = 0; b < 4; ++b) {
    float v = local[b];
    for (int off = 32; off > 0; off >>= 1) v += __shfl_down(v, off);
    if ((tid & 63) == 0) atomicAdd(&accB[b], v);
  }
  __syncthreads();
  if (tid == 0) {
    float tot = 0.f;
    for (int b = 0; b < 4; ++b) tot += accB[b] / (float)Karr[b];
    out[0] = tot;
  }
}

// ---------------------------------------------------------------------------
extern "C" void kernel_launch(void* const* d_in, const int* in_sizes, int n_in,
                              void* d_out, int out_size, void* d_ws, size_t ws_size,
                              hipStream_t stream) {
  const float* x      = (const float*)d_in[0];
  const float* points = (const float*)d_in[1];
  const float* W1 = (const float*)d_in[2];
  const float* b1 = (const float*)d_in[3];
  const float* W2 = (const float*)d_in[4];
  const float* b2 = (const float*)d_in[5];
  const float* W3 = (const float*)d_in[6];
  const float* b3 = (const float*)d_in[7];
  float* out = (float*)d_out;

  char* wsb = (char*)d_ws;
  size_t off = 0;
  auto carve = [&](size_t bytes) -> void* {
    void* r = wsb + off;
    off += (bytes + 255) & ~(size_t)255;
    return r;
  };
  float* sq      = (float*)carve((size_t)B_ * N_ * 4);
  int* p         = (int*)carve((size_t)B_ * N_ * 4);
  int* q         = (int*)carve((size_t)B_ * N_ * 4);
  int* lab       = (int*)carve((size_t)B_ * N_ * 4);
  int* labs      = (int*)carve((size_t)B_ * N_ * 4);
  int* Msz       = (int*)carve((size_t)B_ * N_ * 4);
  int* Karr      = (int*)carve(256);
  int* mcnt      = (int*)carve(256);
  int* totK      = (int*)carve(256);
  f16* Xhi       = (f16*)carve((size_t)B_ * N_ * F_ * 2);
  int* mlist     = (int*)carve((size_t)MAXLIST * 4);
  int* sel       = (int*)carve((size_t)MAXC * DS * 4);
  int* meta      = (int*)carve((size_t)MAXC * 4);
  float* lossArr = (float*)carve((size_t)MAXC * 4);
  (void)ws_size;

  hipLaunchKernelGGL(pre_kernel, dim3(B_ * N_ * F_ / 1024), dim3(256), 0, stream,
                     x, sq, Xhi, p, q, mcnt);
  hipLaunchKernelGGL(distmf_kernel, dim3(528 * B_), dim3(256), 0, stream,
                     Xhi, sq, p, q, mlist, mcnt);
  hipLaunchKernelGGL(fixup_kernel, dim3(512), dim3(256), 0, stream, x, sq, mlist, mcnt, p, q);
  hipLaunchKernelGGL(cluster_kernel, dim3(B_), dim3(1024), 0, stream,
                     p, q, lab, Karr, labs, Msz);
  hipLaunchKernelGGL(rngsel_kernel, dim3(1), dim3(64), 0, stream, Karr, Msz, sel, meta, totK);
  hipLaunchKernelGGL(classify_par_kernel, dim3(512), dim3(256), 0, stream,
                     points, W1, b1, W2, b2, W3, b3, lab, labs, sel, meta, totK, lossArr);
  hipLaunchKernelGGL(reduce_kernel, dim3(1), dim3(256), 0, stream,
                     lossArr, meta, totK, Karr, out);
}